// Round 14
// baseline (614.410 us; speedup 1.0000x reference)
//
#include <hip/hip_runtime.h>
#include <hip/hip_bf16.h>
#include <math.h>

// ---- problem constants -----------------------------------------------------
#define B_    16
#define H_    22
#define W_    20480
#define EMB   35
#define GH_   11
#define GW_   1280
#define L_    1280
#define DM_   385
#define DI_   256
#define N_    4
#define K_    4
#define DTR_  25
#define ROWS_ (B_*L_)              // 20480
#define NX_   ((long)ROWS_*DM_)    // 7,884,800
#define LDM_  ((long)L_*DM_)       // 492,800
#define CH_   64                   // scan chunks
#define CHL_  20                   // steps per chunk (CH_*CHL_ == L_)
#define KPI_  800                  // in_proj W K' (2 terms x 400)
#define KPA_  400                  // in_proj A width (q stored once, padded)
#define KPO_  768                  // out/xp W K' (3 terms x 256)
#define WAO_  512                  // out/xp A width ({hi,lo})

// amax scalars: 8 slots x 64B apart to break single-address atomic serialization
#define NSLOT 8
#define SSTR  16                   // floats between slots (64 B)
#define SCALW 128                  // floats per logical scalar (8 slots)

typedef __attribute__((ext_vector_type(8))) short short8;
typedef __attribute__((ext_vector_type(4))) float f32x4;
typedef unsigned short ushort;

#if defined(__has_builtin)
#if __has_builtin(__builtin_amdgcn_global_load_lds)
#define USE_GLD 1
#endif
#endif
#ifndef USE_GLD
#define USE_GLD 0
#endif

// ---- helpers ---------------------------------------------------------------
__device__ __forceinline__ void atomicMaxF(float* a, float v) {
  atomicMax(reinterpret_cast<int*>(a), __float_as_int(v));
}

// faithful fq: s = max(mx,1e-8)/127 where mx = max over the 8 slots
__device__ __forceinline__ float fq_scale(const float* pmax) {
  float m = pmax[0];
  #pragma unroll
  for (int i = 1; i < NSLOT; i++) m = fmaxf(m, pmax[i * SSTR]);
  return fmaxf(m, 1e-8f) / 127.f;
}
__device__ __forceinline__ float fq_apply(float x, float s) {
  float r = rintf(x / s);
  r = fminf(fmaxf(r, -128.f), 127.f);
  return r * s;
}

__device__ __forceinline__ ushort f2bf(float f) {  // round-to-nearest-even
  union { float f; unsigned u; } v; v.f = f;
  unsigned r = v.u + 0x7FFF + ((v.u >> 16) & 1);
  return (ushort)(r >> 16);
}
__device__ __forceinline__ float bf2f(ushort h) {
  union { unsigned u; float f; } v; v.u = ((unsigned)h) << 16;
  return v.f;
}

// block max -> atomicMax into one of 8 slots (by block id). sm >= blockDim/64.
__device__ __forceinline__ void blockAtomicMax(float v, float* out, float* sm) {
  #pragma unroll
  for (int o = 32; o > 0; o >>= 1) v = fmaxf(v, __shfl_down(v, o));
  if ((threadIdx.x & 63) == 0) sm[threadIdx.x >> 6] = v;
  __syncthreads();
  if (threadIdx.x == 0) {
    int nw = (blockDim.x + 63) >> 6;
    for (int i = 1; i < nw; i++) v = fmaxf(v, sm[i]);
    int slot = (blockIdx.x + blockIdx.y * 4 + blockIdx.z) & (NSLOT - 1);
    atomicMaxF(out + slot * SSTR, v);
  }
}

// ---- setup: weight splits + A2IN pad zero + scalar zero, one launch ---------
__device__ __forceinline__ void wsplit_body(const float* __restrict__ W,
                                            ushort* __restrict__ out,
                                            int K, int N, int Kw, int Kp,
                                            long total, int terms, long idx) {
  if (idx >= total) return;
  int k = (int)(idx % Kp);
  int n = (int)(idx / Kp);
  int t = k / Kw, kk = k - t * Kw;
  ushort r = 0;
  if (n < N && kk < K) {
    float w = W[(long)kk * N + n];
    ushort hi = f2bf(w);
    r = (t == terms - 1) ? f2bf(w - bf2f(hi)) : hi;
  }
  out[idx] = r;
}

__global__ __launch_bounds__(256) void k_setup(const float* __restrict__ in_w,
                                               const float* __restrict__ outw,
                                               const float* __restrict__ xpw,
                                               ushort* __restrict__ W2TI,
                                               ushort* __restrict__ W2TO,
                                               ushort* __restrict__ W2TX,
                                               ushort* __restrict__ A2IN,
                                               float* __restrict__ SCAL) {
  int bid = blockIdx.x;
  if (bid < 3200) {                       // in_w splits (2 x 1600)
    int blk = bid / 1600;
    long idx = (long)(bid % 1600) * 256 + threadIdx.x;
    wsplit_body(in_w + (long)blk * DM_ * 512, W2TI + (long)blk * 512 * KPI_,
                DM_, 512, KPA_, KPI_, 512L * KPI_, 2, idx);
    return;
  }
  bid -= 3200;
  if (bid < 3072) {                       // outw splits (2 x 1536)
    int blk = bid / 1536;
    long idx = (long)(bid % 1536) * 256 + threadIdx.x;
    wsplit_body(outw + (long)blk * DI_ * DM_, W2TO + (long)blk * 512 * KPO_,
                DI_, DM_, 256, KPO_, 512L * KPO_, 3, idx);
    return;
  }
  bid -= 3072;
  if (bid < 768) {                        // xpw splits (2 x 384)
    int blk = bid / 384;
    long idx = (long)(bid % 384) * 256 + threadIdx.x;
    wsplit_body(xpw + (long)blk * DI_ * 33, W2TX + (long)blk * 128 * KPO_,
                DI_, 33, 256, KPO_, 128L * KPO_, 3, idx);
    return;
  }
  bid -= 768;
  if (bid < 1200) {                       // A2IN pad zero (ROWS_*15 elems)
    long idx = (long)bid * 256 + threadIdx.x;
    long m = idx / 15; int c = (int)(idx - m * 15);
    A2IN[m * KPA_ + 385 + c] = 0;
    return;
  }
  bid -= 1200;                            // zero 8*256 scalar floats
  SCAL[bid * 256 + threadIdx.x] = 0.f;
}

// ---- fused absmax of x (1024 blk), pos (256 blk), pew (1 blk), float4 -------
__global__ __launch_bounds__(256) void k_absmax3(const float* __restrict__ x,
                                                 const float* __restrict__ pos,
                                                 const float* __restrict__ pew,
                                                 float* __restrict__ sx,
                                                 float* __restrict__ spos,
                                                 float* __restrict__ spew) {
  __shared__ float smr[8];
  int bid = blockIdx.x;
  float m = 0.f;
  if (bid < 1024) {
    const float4* p = (const float4*)x;
    const long n4 = (long)B_ * H_ * W_ / 4;
    for (long i = (long)bid * 256 + threadIdx.x; i < n4; i += 1024L * 256) {
      float4 v = p[i];
      m = fmaxf(m, fmaxf(fmaxf(fabsf(v.x), fabsf(v.y)), fmaxf(fabsf(v.z), fabsf(v.w))));
    }
    blockAtomicMax(m, sx, smr);
  } else if (bid < 1280) {
    const float4* p = (const float4*)pos;
    const long n4 = LDM_ / 4;
    for (long i = (long)(bid - 1024) * 256 + threadIdx.x; i < n4; i += 256L * 256) {
      float4 v = p[i];
      m = fmaxf(m, fmaxf(fmaxf(fabsf(v.x), fabsf(v.y)), fmaxf(fabsf(v.z), fabsf(v.w))));
    }
    blockAtomicMax(m, spos, smr);
  } else {
    for (int i = threadIdx.x; i < EMB * 32; i += 256) m = fmaxf(m, fabsf(pew[i]));
    blockAtomicMax(m, spew, smr);
  }
}

// simple elementwise fq into a fresh buffer (patch weights only; tiny)
__global__ void k_qx(const float* __restrict__ src, float* __restrict__ dst, long n,
                     const float* __restrict__ pmax) {
  float s = fq_scale(pmax);
  for (long i = (long)blockIdx.x * blockDim.x + threadIdx.x; i < n;
       i += (long)gridDim.x * blockDim.x)
    dst[i] = fq_apply(src[i], s);
}

// vectorized fq: dst4 = fq(src4); optional absmax -> nextmax; optional bf16
// q-emit into A2 [M][KPA_]. dst may == src.
__global__ void k_fq4(const float4* __restrict__ src, float4* __restrict__ dst, long n4,
                      const float* __restrict__ pmax, float* __restrict__ nextmax,
                      ushort* __restrict__ a2) {
  __shared__ float smr[8];
  float s = fq_scale(pmax);
  float m = 0.f;
  for (long i = (long)blockIdx.x * blockDim.x + threadIdx.x; i < n4;
       i += (long)gridDim.x * blockDim.x) {
    float4 v = src[i];
    float r0 = fminf(fmaxf(rintf(v.x / s), -128.f), 127.f);
    float r1 = fminf(fmaxf(rintf(v.y / s), -128.f), 127.f);
    float r2 = fminf(fmaxf(rintf(v.z / s), -128.f), 127.f);
    float r3 = fminf(fmaxf(rintf(v.w / s), -128.f), 127.f);
    float4 q = make_float4(r0 * s, r1 * s, r2 * s, r3 * s);
    dst[i] = q;
    m = fmaxf(m, fmaxf(fmaxf(fabsf(q.x), fabsf(q.y)), fmaxf(fabsf(q.z), fabsf(q.w))));
    if (a2) {
      long ii = i * 4;
      long mm = ii / 385; int kk = (int)(ii - mm * 385);
      float rr[4] = {r0, r1, r2, r3};
      #pragma unroll
      for (int j = 0; j < 4; j++) {
        a2[mm * KPA_ + kk] = f2bf(rr[j]);
        if (++kk == 385) { kk = 0; mm++; }
      }
    }
  }
  if (nextmax) blockAtomicMax(m, nextmax, smr);
}

// x4[i] = fq(x4[i], s_pmax) + p2[i % LDM/4]; absmax -> nextmax
__global__ void k_addpos4(float4* __restrict__ x, const float4* __restrict__ p2,
                          const float* __restrict__ pmax, float* __restrict__ nextmax) {
  __shared__ float smr[8];
  float s = fq_scale(pmax);
  float m = 0.f;
  const long n4 = NX_ / 4, l4 = LDM_ / 4;
  for (long i = (long)blockIdx.x * blockDim.x + threadIdx.x; i < n4;
       i += (long)gridDim.x * blockDim.x) {
    float4 v = x[i];
    float4 p = p2[i % l4];
    float4 o;
    o.x = fq_apply(v.x, s) + p.x;
    o.y = fq_apply(v.y, s) + p.y;
    o.z = fq_apply(v.z, s) + p.z;
    o.w = fq_apply(v.w, s) + p.w;
    x[i] = o;
    m = fmaxf(m, fmaxf(fmaxf(fabsf(o.x), fabsf(o.y)), fmaxf(fabsf(o.z), fabsf(o.w))));
  }
  blockAtomicMax(m, nextmax, smr);
}

// ---- fused patch embed: LDS-staged x (fq inline), PRE-QUANTIZED weights -----
__global__ __launch_bounds__(320) void k_patchfq(const float* __restrict__ x,
                                                 const float* __restrict__ wq,
                                                 const float* __restrict__ peb,
                                                 const float* __restrict__ sx_,
                                                 float* __restrict__ out,
                                                 float* __restrict__ nextmax) {
  __shared__ float xs[2][64][20];   // [ph][gw_local][pw] padded to 20
  __shared__ float smr[8];
  int tid = threadIdx.x;
  int gwt = blockIdx.x, gh = blockIdx.y, b = blockIdx.z;
  float sx = fq_scale(sx_);
  if (tid < 256) {
    int gwl = tid >> 2, pw = (tid & 3) * 4;
    #pragma unroll
    for (int ph = 0; ph < 2; ph++) {
      const float* src = x + ((long)b * H_ + gh * 2 + ph) * W_ + (long)gwt * 1024 + tid * 4;
      float4 v = *reinterpret_cast<const float4*>(src);
      xs[ph][gwl][pw + 0] = fq_apply(v.x, sx);
      xs[ph][gwl][pw + 1] = fq_apply(v.y, sx);
      xs[ph][gwl][pw + 2] = fq_apply(v.z, sx);
      xs[ph][gwl][pw + 3] = fq_apply(v.w, sx);
    }
  }
  __syncthreads();
  float mx = 0.f;
  if (tid < 280) {
    int e = tid % 35;
    int g0 = (tid / 35) * 8;
    float w[32];
    #pragma unroll
    for (int j = 0; j < 32; j++) w[j] = wq[e * 32 + j];
    float bias = peb[e];
    long obase = ((long)b * GW_ + (long)gwt * 64) * DM_ + gh * 35 + e;
    #pragma unroll
    for (int gi = 0; gi < 8; gi++) {
      int gw = g0 + gi;
      float acc = bias;
      #pragma unroll
      for (int pw = 0; pw < 16; pw++) {
        acc = fmaf(xs[0][gw][pw], w[pw], acc);
        acc = fmaf(xs[1][gw][pw], w[16 + pw], acc);
      }
      out[obase + (long)gw * DM_] = acc;
      mx = fmaxf(mx, fabsf(acc));
    }
  }
  blockAtomicMax(mx, nextmax, smr);
}

// ---- activation split: (Y0+Y1)[M][256] f32 -> A2[M][512] bf16 {hi,lo} -------
__global__ void k_asplit2(const float* __restrict__ Y, ushort* __restrict__ A2) {
  long idx = (long)blockIdx.x * 256 + threadIdx.x;   // M*512 threads
  long m = idx >> 9; int k = (int)(idx & 511);
  int t = k >> 8, kk = k & 255;
  float v = Y[m * DI_ + kk] + Y[(m + ROWS_) * DI_ + kk];
  ushort hi = f2bf(v);
  A2[idx] = t ? f2bf(v - bf2f(hi)) : hi;
}

// ---- bf16 MFMA GEMM: C[M][Nreal] = scale * (A2[M][Wa,wrapped] @ W2T[Npad][Kp]^T)
// Linear LDS tile [128 rows][32 k] (lane-linear writes); staged via
// global_load_lds width 16 (no VGPR round-trip, no ds_write) when available.
// 1-D grid NT*MT (m = bid%MT, n = bid/MT): same-m blocks share XCD L2 A-panel.
template<bool AMAX>
__global__ __launch_bounds__(256) void k_mgemm(const ushort* __restrict__ A2,
                                               const ushort* __restrict__ W2T,
                                               float* __restrict__ C,
                                               int Nreal, int Kp, int Wa, int MT,
                                               const float* __restrict__ sptr,
                                               float* __restrict__ amax_out) {
  __shared__ ushort Alds[4096];   // [row][32] linear, 8 KB
  __shared__ ushort Blds[4096];
  __shared__ float smr[8];
  int tid = threadIdx.x;
  int lane = tid & 63, wave = tid >> 6;
  int wm = wave >> 1, wn = wave & 1;
  int bid = blockIdx.x;
  int m0 = (bid % MT) * 128, n0 = (bid / MT) * 128;
  f32x4 acc[4][4];
  #pragma unroll
  for (int i = 0; i < 4; i++)
    #pragma unroll
    for (int j = 0; j < 4; j++) acc[i][j] = (f32x4){0.f, 0.f, 0.f, 0.f};

  for (int k0 = 0; k0 < Kp; k0 += 32) {
    #pragma unroll
    for (int r = 0; r < 2; r++) {
      int id = tid + r * 256;            // 0..511
      int row = id >> 2, sl = id & 3;    // 64B global segments per row
      int kc = k0 + sl * 8; if (kc >= Wa) kc -= Wa;   // A k-wrap (8-aligned)
      const ushort* ga = A2 + (long)(m0 + row) * Wa + kc;
      const ushort* gb = W2T + (long)(n0 + row) * Kp + k0 + sl * 8;
#if USE_GLD
      __builtin_amdgcn_global_load_lds(
          (const __attribute__((address_space(1))) unsigned int*)ga,
          (__attribute__((address_space(3))) unsigned int*)(Alds + id * 8), 16, 0, 0);
      __builtin_amdgcn_global_load_lds(
          (const __attribute__((address_space(1))) unsigned int*)gb,
          (__attribute__((address_space(3))) unsigned int*)(Blds + id * 8), 16, 0, 0);
#else
      short8 va = *reinterpret_cast<const short8*>(ga);
      *reinterpret_cast<short8*>(&Alds[id * 8]) = va;
      short8 vb = *reinterpret_cast<const short8*>(gb);
      *reinterpret_cast<short8*>(&Blds[id * 8]) = vb;
#endif
    }
    __syncthreads();
    int sl = lane >> 4, rr = lane & 15;
    short8 af[4], bf4[4];
    #pragma unroll
    for (int i = 0; i < 4; i++)
      af[i] = *reinterpret_cast<const short8*>(&Alds[(wm * 64 + i * 16 + rr) * 32 + sl * 8]);
    #pragma unroll
    for (int j = 0; j < 4; j++)
      bf4[j] = *reinterpret_cast<const short8*>(&Blds[(wn * 64 + j * 16 + rr) * 32 + sl * 8]);
    #pragma unroll
    for (int i = 0; i < 4; i++)
      #pragma unroll
      for (int j = 0; j < 4; j++)
        acc[i][j] = __builtin_amdgcn_mfma_f32_16x16x32_bf16(af[i], bf4[j], acc[i][j], 0, 0, 0);
    __syncthreads();
  }

  float s = sptr ? fq_scale(sptr) : 1.0f;
  float mx = 0.f;
  int cfr = lane & 15, rbase = (lane >> 4) * 4;
  #pragma unroll
  for (int i = 0; i < 4; i++) {
    int gmb = m0 + wm * 64 + i * 16 + rbase;
    #pragma unroll
    for (int j = 0; j < 4; j++) {
      int gn = n0 + wn * 64 + j * 16 + cfr;
      if (gn < Nreal) {
        #pragma unroll
        for (int rg = 0; rg < 4; rg++) {
          float v = acc[i][j][rg] * s;
          C[(long)(gmb + rg) * Nreal + gn] = v;
          mx = fmaxf(mx, fabsf(v));
        }
      }
    }
  }
  if (AMAX) blockAtomicMax(mx, amax_out, smr);
}

// ---- depthwise causal conv1d (K=4) + SiLU, BOTH dirs from one window --------
__global__ __launch_bounds__(256) void k_conv2(const float* __restrict__ xz,
                                               const float* __restrict__ cw,
                                               const float* __restrict__ cb,
                                               ushort* __restrict__ xch) {
  int d = threadIdx.x;
  int t0 = blockIdx.x * 16, b = blockIdx.y;
  long base = (long)b * L_;
  float w0 = cw[d * 4 + 0], w1 = cw[d * 4 + 1];
  float w2 = cw[d * 4 + 2], w3 = cw[d * 4 + 3];
  float bias = cb[d];
  float win[22];
  #pragma unroll
  for (int i = 0; i < 22; i++) {
    int t = t0 - 3 + i;
    win[i] = (t >= 0 && t < L_) ? xz[(base + t) * (2 * DI_) + d] : 0.f;
  }
  #pragma unroll
  for (int i = 0; i < 16; i++) {
    int t = t0 + i;
    float a0 = bias;
    a0 = fmaf(w0, win[i + 0], a0);
    a0 = fmaf(w1, win[i + 1], a0);
    a0 = fmaf(w2, win[i + 2], a0);
    a0 = fmaf(w3, win[i + 3], a0);
    float a1 = bias;
    a1 = fmaf(w0, win[i + 6], a1);
    a1 = fmaf(w1, win[i + 5], a1);
    a1 = fmaf(w2, win[i + 4], a1);
    a1 = fmaf(w3, win[i + 3], a1);
    float v0 = a0 * (1.f / (1.f + expf(-a0)));
    float v1 = a1 * (1.f / (1.f + expf(-a1)));
    long g0o = (base + t) * 512 + d;
    ushort h0 = f2bf(v0), h1 = f2bf(v1);
    xch[g0o] = h0;
    xch[g0o + 256] = f2bf(v0 - bf2f(h0));
    long g1o = ((long)ROWS_ + base + t) * 512 + d;
    xch[g1o] = h1;
    xch[g1o + 256] = f2bf(v1 - bf2f(h1));
  }
}

// ---- dt precompute into Y (scan2 reads dt then overwrites with y in place) --
__device__ __forceinline__ float softplusf(float x) {
  return fmaxf(x, 0.f) + log1pf(expf(-fabsf(x)));
}

__global__ __launch_bounds__(256) void k_dtp(const float* __restrict__ proj,
                                             const float* __restrict__ dtw,
                                             const float* __restrict__ dtb,
                                             float* __restrict__ dty) {
  __shared__ float pr[16][26];
  int d = threadIdx.x;
  long g0 = (long)blockIdx.x * 16;
  for (int i = threadIdx.x; i < 16 * DTR_; i += 256) {
    int r = i / DTR_, j = i - r * DTR_;
    pr[r][j] = proj[(g0 + r) * 33 + j];
  }
  float dwr[DTR_];
  #pragma unroll
  for (int r = 0; r < DTR_; r++) dwr[r] = dtw[r * DI_ + d];
  float dbv = dtb[d];
  __syncthreads();
  #pragma unroll
  for (int r = 0; r < 16; r++) {
    float acc = dbv;
    #pragma unroll
    for (int j = 0; j < DTR_; j++) acc = fmaf(pr[r][j], dwr[j], acc);
    dty[(g0 + r) * DI_ + d] = softplusf(acc);
  }
}

// ---- chunked parallel selective scan (exp-reduced, both dirs in grid.z) -----
__global__ __launch_bounds__(256) void k_scan1(const ushort* __restrict__ xch,
                                               const float* __restrict__ proj,
                                               const float* __restrict__ A_log,
                                               const float* __restrict__ dty,
                                               float* __restrict__ Hend,
                                               float* __restrict__ Pend) {
  int b = blockIdx.y, c = blockIdx.x, d = threadIdx.x, dir = blockIdx.z;
  float A[4];
  #pragma unroll
  for (int n = 0; n < 4; n++) A[n] = -expf(A_log[d * 4 + n]);
  bool fast = true;
  #pragma unroll
  for (int n = 1; n < 4; n++)
    fast = fast && (fabsf(A[n] - (float)(n + 1) * A[0]) <= 1e-4f * fabsf(A[n]));
  long base = (long)b * L_;
  int step0 = c * CHL_;
  long row0 = base + (dir ? (L_ - 1 - step0) : step0);
  long doff = (long)dir * ROWS_;
  int rs = dir ? -1 : 1;
  const float* pdt = dty + (doff + row0) * DI_ + d;
  const ushort* pxc = xch + (doff + row0) * 512 + d;
  const float* pp  = proj + (doff + row0) * 33;
  float h[4] = {0.f, 0.f, 0.f, 0.f};
  float sdt = 0.f;
  if (fast) {
    float A0 = A[0];
    for (int s = 0; s < CHL_; s++) {
      float dtv = *pdt;
      float xcv = bf2f(pxc[0]) + bf2f(pxc[256]);
      float dx = dtv * xcv;
      float e1 = expf(dtv * A0);
      float e2 = e1 * e1, e3 = e2 * e1, e4 = e3 * e1;
      h[0] = e1 * h[0] + dx * pp[DTR_ + 0];
      h[1] = e2 * h[1] + dx * pp[DTR_ + 1];
      h[2] = e3 * h[2] + dx * pp[DTR_ + 2];
      h[3] = e4 * h[3] + dx * pp[DTR_ + 3];
      sdt += dtv;
      pdt += (long)rs * DI_; pxc += (long)rs * 512; pp += rs * 33;
    }
  } else {
    for (int s = 0; s < CHL_; s++) {
      float dtv = *pdt;
      float xcv = bf2f(pxc[0]) + bf2f(pxc[256]);
      float dx = dtv * xcv;
      #pragma unroll
      for (int n = 0; n < 4; n++) {
        float dA = expf(dtv * A[n]);
        h[n] = dA * h[n] + dx * pp[DTR_ + n];
      }
      sdt += dtv;
      pdt += (long)rs * DI_; pxc += (long)rs * 512; pp += rs * 33;
    }
  }
  float P[4];
  #pragma unroll
  for (int n = 0; n < 4; n++) P[n] = expf(A[n] * sdt);
  long o = (((long)dir * B_ + b) * CH_ + c) * 1024 + d * 4;
  *reinterpret_cast<float4*>(Hend + o) = make_float4(h[0], h[1], h[2], h[3]);
  *reinterpret_cast<float4*>(Pend + o) = make_float4(P[0], P[1], P[2], P[3]);
}

__global__ __launch_bounds__(256) void k_carry(const float* __restrict__ Hend,
                                               const float* __restrict__ Pend,
                                               float* __restrict__ Carry) {
  int tid = blockIdx.x * 256 + threadIdx.x;   // 2*B_*1024 lanes
  int be = tid >> 10, i = tid & 1023;         // be = dir*16+b
  float carry = 0.f;
  for (int c = 0; c < CH_; c++) {
    long o = ((long)be * CH_ + c) * 1024 + i;
    Carry[o] = carry;
    carry = Pend[o] * carry + Hend[o];
  }
}

// dty holds dt on entry; read-once-then-overwrite with y (same thread).
__global__ __launch_bounds__(256) void k_scan2(const ushort* __restrict__ xch,
                                               const float* __restrict__ proj,
                                               const float* __restrict__ A_log,
                                               const float* __restrict__ Dp,
                                               const float* __restrict__ xz,
                                               const float* __restrict__ Carry,
                                               float* dty) {
  int b = blockIdx.y, c = blockIdx.x, d = threadIdx.x, dir = blockIdx.z;
  float A[4];
  #pragma unroll
  for (int n = 0; n < 4; n++) A[n] = -expf(A_log[d * 4 + n]);
  bool fast = true;
  #pragma unroll
  for (int n = 1; n < 4; n++)
    fast = fast && (fabsf(A[n] - (float)(n + 1) * A[0]) <= 1e-4f * fabsf(A[n]));
  long base = (long)b * L_;
  int step0 = c * CHL_;
  long row0 = base + (dir ? (L_ - 1 - step0) : step0);
  long doff = (long)dir * ROWS_;
  int rs = dir ? -1 : 1;
  float* pdy = dty + (doff + row0) * DI_ + d;
  const ushort* pxc = xch + (doff + row0) * 512 + d;
  const float* pz  = xz + row0 * (2 * DI_) + DI_ + d;
  const float* pp  = proj + (doff + row0) * 33;
  long o = (((long)dir * B_ + b) * CH_ + c) * 1024 + d * 4;
  float4 cv = *reinterpret_cast<const float4*>(Carry + o);
  float h[4] = {cv.x, cv.y, cv.z, cv.w};
  float Dv = Dp[d];
  if (fast) {
    float A0 = A[0];
    for (int s = 0; s < CHL_; s++) {
      float dtv = *pdy;
      float xcv = bf2f(pxc[0]) + bf2f(pxc[256]);
      float zv  = *pz;
      float dx = dtv * xcv;
      float e1 = expf(dtv * A0);
      float e2 = e1 * e1, e3 = e2 * e1, e4 = e3 * e1;
      h[0] = e1 * h[0] + dx * pp[DTR_ + 0];
      h[1] = e2 * h[1] + dx * pp[DTR_ + 1];
      h[2] = e3 * h[2] + dx * pp[DTR_ + 2];
      h[3] = e4 * h[3] + dx * pp[DTR_ + 3];
      float acc = 0.f;
      acc = fmaf(h[0], pp[DTR_ + N_ + 0], acc);
      acc = fmaf(h[1], pp[DTR_ + N_ + 1], acc);
      acc = fmaf(h[2], pp[DTR_ + N_ + 2], acc);
      acc = fmaf(h[3], pp[DTR_ + N_ + 3], acc);
      float yv = fmaf(Dv, xcv, acc);
      float sig = 1.f / (1.f + expf(-zv));
      yv *= zv * sig;
      *pdy = yv;
      pdy += (long)rs * DI_; pxc += (long)rs * 512;
      pz += rs * (2 * DI_); pp += rs * 33;
    }
  } else {
    for (int s = 0; s < CHL_; s++) {
      float dtv = *pdy;
      float xcv = bf2f(pxc[0]) + bf2f(pxc[256]);
      float zv  = *pz;
      float dx = dtv * xcv;
      float acc = 0.f;
      #pragma unroll
      for (int n = 0; n < 4; n++) {
        float dA = expf(dtv * A[n]);
        h[n] = dA * h[n] + dx * pp[DTR_ + n];
        acc = fmaf(h[n], pp[DTR_ + N_ + n], acc);
      }
      float yv = fmaf(Dv, xcv, acc);
      float sig = 1.f / (1.f + expf(-zv));
      yv *= zv * sig;
      *pdy = yv;
      pdy += (long)rs * DI_; pxc += (long)rs * 512;
      pz += rs * (2 * DI_); pp += rs * 33;
    }
  }
}

// ---- residual + fq(mamba_out) + layernorm, wave-per-row ----------------------
__global__ __launch_bounds__(256) void k_ln(const float* __restrict__ x2,
                                            float* __restrict__ mo,
                                            const float* __restrict__ smo,
                                            const float* __restrict__ g,
                                            const float* __restrict__ bta,
                                            float* __restrict__ nextmax) {
  __shared__ float smr[4];
  int lane = threadIdx.x & 63;
  int wid = blockIdx.x * 4 + (threadIdx.x >> 6);
  float s = fq_scale(smo);
  float wmax = 0.f;
  for (int row = wid; row < ROWS_; row += 2560) {
    const float* xr = x2 + (long)row * DM_;
    float* mr = mo + (long)row * DM_;
    float v[7];
    float lsum = 0.f;
    #pragma unroll
    for (int k = 0; k < 6; k++) {
      int c = lane + k * 64;
      v[k] = xr[c] + fq_apply(mr[c], s);
      lsum += v[k];
    }
    v[6] = 0.f;
    if (lane == 0) v[6] = xr[384] + fq_apply(mr[384], s);
    lsum += v[6];
    #pragma unroll
    for (int o = 32; o > 0; o >>= 1) lsum += __shfl_xor(lsum, o);
    float mean = lsum / 385.f;
    float lvar = 0.f;
    #pragma unroll
    for (int k = 0; k < 6; k++) { float dd = v[k] - mean; lvar += dd * dd; }
    if (lane == 0) { float dd = v[6] - mean; lvar += dd * dd; }
    #pragma unroll
    for (int o = 32; o > 0; o >>= 1) lvar += __shfl_xor(lvar, o);
    float rs = 1.f / sqrtf(lvar / 385.f + 1e-5f);
    #pragma unroll
    for (int k = 0; k < 6; k++) {
      int c = lane + k * 64;
      float o2 = (v[k] - mean) * rs * g[c] + bta[c];
      mr[c] = o2;
      wmax = fmaxf(wmax, fabsf(o2));
    }
    if (lane == 0) {
      float o2 = (v[6] - mean) * rs * g[384] + bta[384];
      mr[384] = o2;
      wmax = fmaxf(wmax, fabsf(o2));
    }
  }
  blockAtomicMax(wmax, nextmax, smr);
}

// ---- mean pool over L (two-stage, coalesced, deterministic) ------------------
__global__ __launch_bounds__(256) void k_pool1(const float* __restrict__ x2,
                                               float* __restrict__ part) {
  int b = blockIdx.x, ch = blockIdx.y, tid = threadIdx.x;
  float s0 = 0.f, s1 = 0.f;
  for (int l = ch * 64; l < ch * 64 + 64; l++) {
    const float* row = x2 + ((long)b * L_ + l) * DM_;
    s0 += row[tid];
    if (tid < DM_ - 256) s1 += row[tid + 256];
  }
  long o = ((long)b * 20 + ch) * DM_;
  part[o + tid] = s0;
  if (tid < DM_ - 256) part[o + tid + 256] = s1;
}

// blocks 0..24: pool reduce + amax(pool) -> spool; blocks 25..28: amax(clsw) -> sclsw
__global__ void k_pool2c(const float* __restrict__ part, float* __restrict__ pool,
                         const float* __restrict__ clsw,
                         float* __restrict__ spool, float* __restrict__ sclsw) {
  __shared__ float smr[8];
  int bid = blockIdx.x;
  if (bid < 25) {
    int idx = bid * 256 + threadIdx.x;
    float mv = 0.f;
    if (idx < B_ * DM_) {
      int b = idx / DM_, c = idx % DM_;
      float s = 0.f;
      for (int ch = 0; ch < 20; ch++) s += part[((long)b * 20 + ch) * DM_ + c];
      float mean = s / (float)L_;
      pool[idx] = mean;
      mv = fabsf(mean);
    }
    blockAtomicMax(mv, spool, smr);
  } else {
    float m = 0.f;
    for (int i = (bid - 25) * 256 + threadIdx.x; i < DM_ * 2; i += 4 * 256)
      m = fmaxf(m, fabsf(clsw[i]));
    blockAtomicMax(m, sclsw, smr);
  }
}

// ---- classifier (parallel): grid 32 = (b,c), 128 threads reduce over K=385 --
__global__ __launch_bounds__(128) void k_cls(const float* __restrict__ pool,
                                             const float* __restrict__ clsw,
                                             const float* __restrict__ clsb,
                                             const float* __restrict__ sp_,
                                             const float* __restrict__ sw_,
                                             float* __restrict__ out) {
  __shared__ float smr[2];
  int b = blockIdx.x >> 1, c = blockIdx.x & 1;
  float sp = fq_scale(sp_), sw = fq_scale(sw_);
  float acc = 0.f;
  for (int k = threadIdx.x; k < DM_; k += 128) {
    float xv = fq_apply(pool[b * DM_ + k], sp);
    float wv = fq_apply(clsw[k * 2 + c], sw);
    acc = fmaf(xv, wv, acc);
  }
  #pragma unroll
  for (int o = 32; o > 0; o >>= 1) acc += __shfl_down(acc, o);
  if ((threadIdx.x & 63) == 0) smr[threadIdx.x >> 6] = acc;
  __syncthreads();
  if (threadIdx.x == 0) out[blockIdx.x] = smr[0] + smr[1] + clsb[c];
}

// ---- launch ------------------------------------------------------------------
extern "C" void kernel_launch(void* const* d_in, const int* in_sizes, int n_in,
                              void* d_out, int out_size, void* d_ws, size_t ws_size,
                              hipStream_t stream) {
  const float* x    = (const float*)d_in[0];
  const float* pew  = (const float*)d_in[1];
  const float* peb  = (const float*)d_in[2];
  const float* pos  = (const float*)d_in[3];
  const float* in_w = (const float*)d_in[4];
  const float* cw   = (const float*)d_in[5];
  const float* cb   = (const float*)d_in[6];
  const float* xpw  = (const float*)d_in[7];
  const float* dtw  = (const float*)d_in[8];
  const float* dtb  = (const float*)d_in[9];
  const float* alog = (const float*)d_in[10];
  const float* dp   = (const float*)d_in[11];
  const float* outw = (const float*)d_in[12];
  const float* lng  = (const float*)d_in[13];
  const float* lnb  = (const float*)d_in[14];
  const float* clsw = (const float*)d_in[15];
  const float* clsb = (const float*)d_in[16];

  float* ws    = (float*)d_ws;
  float* SCAL  = ws;                              // 13 scalars x 128 floats (8 slots)
  float* WQ    = ws + 2048;                       // 2048 (1120 used)
  float* P2    = WQ + 2048;                       // 492,800
  float* X2    = P2 + LDM_;                       // 7,884,800
  float* XZ    = X2 + NX_;                        // 10,485,760
  float* XCH_f = XZ + (long)ROWS_ * 512;          // 10,485,760 (ushort [40960][512])
  float* PROJ  = XCH_f + 2L * ROWS_ * DI_;        // 40960*33 = 1,351,680
  float* Y     = PROJ + 2L * ROWS_ * 33;          // 2 x 5,242,880 (dt -> y in place)
  float* MO    = Y + 2L * ROWS_ * DI_;            // 7,884,800
  float* POOL  = MO + NX_;                        // 8,192
  float* PART  = POOL + 8192;                     // 123,200 (+pad)
  float* A2IN_f= PART + 131072;                   // 4,096,000 f (ushort overlay)
  float* W2I_f = A2IN_f + 4096000;                // 409,600 f
  float* W2O_f = W2I_f + 409600;                  // 393,216 f
  float* W2X_f = W2O_f + 393216;                  // 98,304 f (2 x [128][768] ushort)
  // aliases (disjoint lifetimes):
  float*  HEND = MO;                              // scan summaries, dead before out-GEMM
  float*  PEND = MO + 2097152;
  float*  CARR = MO + 4194304;
  ushort* A2Y  = (ushort*)XZ;                     // [20480][512], dead before next in-GEMM
  ushort* XCH  = (ushort*)XCH_f;                  // xc bf16 {hi|lo} [40960][512]
  ushort* A2IN = (ushort*)A2IN_f;                 // [20480][400]
  ushort* W2TI = (ushort*)W2I_f;                  // 2 x [512][800]
  ushort* W2TO = (ushort*)W2O_f;                  // 2 x [512][768]
  ushort* W2TX = (ushort*)W2X_f;                  // 2 x [128][768]

  // scalar entry i lives at SCAL + i*SCALW (8 slots, 64B apart)
  #define SC(i) (SCAL + (i) * SCALW)

  // one consolidated setup launch: all weight splits + A2IN pad + SCAL zero
  k_setup<<<8248, 256, 0, stream>>>(in_w, outw, xpw, W2TI, W2TO, W2TX, A2IN, SCAL);

  // fused absmax of x / pos / pew (one launch), then pre-quantize patch weights
  k_absmax3<<<1281, 256, 0, stream>>>(x, pos, pew, SC(0), SC(4), SC(1));
  k_qx<<<5, 256, 0, stream>>>(pew, WQ, EMB * 2 * 16, SC(1));
  k_patchfq<<<dim3(20, 11, 16), 320, 0, stream>>>(x, WQ, peb, SC(0), X2, SC(2));

  // pos = fq(fq(pos_embed)) == fq(pos_embed)  (fq idempotent)
  k_fq4<<<512, 256, 0, stream>>>((const float4*)pos, (float4*)P2, LDM_ / 4,
                                 SC(4), nullptr, nullptr);

  // x = fq(fq(x) + pos) with inner fq(x) = fq(patch_out, s2) (outer chain identity)
  k_addpos4<<<2048, 256, 0, stream>>>((float4*)X2, (const float4*)P2, SC(2), SC(6));
  k_fq4<<<2048, 256, 0, stream>>>((const float4*)X2, (float4*)X2, NX_ / 4,
                                  SC(6), nullptr, A2IN);

  const float* in_scale[2] = {SC(6), SC(8)};
  for (int blk = 0; blk < 2; blk++) {
    // in-proj: XZ = s * (q @ [w_hi; w_lo])   (MFMA bf16, A k-wrapped at 400)
    k_mgemm<false><<<640, 256, 0, stream>>>(
        A2IN, W2TI + (long)blk * 512 * KPI_, XZ, 512, KPI_, KPA_, 160,
        in_scale[blk], nullptr);
    // conv both dirs -> xc bf16 {hi|lo}; xp-proj via MFMA (N=33 in one tile)
    k_conv2<<<dim3(80, 16), 256, 0, stream>>>(XZ, cw + blk * DI_ * K_,
                                              cb + blk * DI_, XCH);
    k_mgemm<false><<<320, 256, 0, stream>>>(
        XCH, W2TX + (long)blk * 128 * KPO_, PROJ, 33, KPO_, WAO_, 320,
        nullptr, nullptr);
    k_dtp<<<2560, 256, 0, stream>>>(PROJ, dtw + blk * DTR_ * DI_, dtb + blk * DI_, Y);
    k_scan1<<<dim3(CH_, B_, 2), 256, 0, stream>>>(XCH, PROJ, alog + blk * DI_ * N_,
                                                  Y, HEND, PEND);
    k_carry<<<128, 256, 0, stream>>>(HEND, PEND, CARR);
    k_scan2<<<dim3(CH_, B_, 2), 256, 0, stream>>>(XCH, PROJ, alog + blk * DI_ * N_,
                                                  dp + blk * DI_, XZ, CARR, Y);
    // out-proj: MO = [y_hi | y_lo] (wrapped) @ [w_hi; w_hi; w_lo]  (amax fused)
    k_asplit2<<<40960, 256, 0, stream>>>(Y, A2Y);
    k_mgemm<true><<<640, 256, 0, stream>>>(
        A2Y, W2TO + (long)blk * 512 * KPO_, MO, DM_, KPO_, WAO_, 160,
        nullptr, SC(7 + blk * 2));
    // x = fq(layernorm(x + fq(mo))); emit q for next block's in-proj
    k_ln<<<640, 256, 0, stream>>>(X2, MO, SC(7 + blk * 2),
                                  lng + blk * DM_, lnb + blk * DM_, SC(8 + blk * 2));
    k_fq4<<<2048, 256, 0, stream>>>((const float4*)MO, (float4*)X2, NX_ / 4,
                                    SC(8 + blk * 2), nullptr,
                                    blk == 0 ? A2IN : nullptr);
  }

  // mean-pool (2-stage, clsw amax folded into stage 2), fq, classifier
  k_pool1<<<dim3(16, 20), 256, 0, stream>>>(X2, PART);
  k_pool2c<<<29, 256, 0, stream>>>(PART, POOL, clsw, SC(11), SC(12));
  k_cls<<<32, 128, 0, stream>>>(POOL, clsw, clsb, SC(11), SC(12), (float*)d_out);
}

// Round 15
// 592.146 us; speedup vs baseline: 1.0376x; 1.0376x over previous
//
#include <hip/hip_runtime.h>
#include <hip/hip_bf16.h>
#include <math.h>

// ---- problem constants -----------------------------------------------------
#define B_    16
#define H_    22
#define W_    20480
#define EMB   35
#define GH_   11
#define GW_   1280
#define L_    1280
#define DM_   385
#define DI_   256
#define N_    4
#define K_    4
#define DTR_  25
#define ROWS_ (B_*L_)              // 20480
#define NX_   ((long)ROWS_*DM_)    // 7,884,800
#define LDM_  ((long)L_*DM_)       // 492,800
#define CH_   64                   // scan chunks
#define CHL_  20                   // steps per chunk (CH_*CHL_ == L_)
#define KPI_  800                  // in_proj W K' (2 terms x 400)
#define KPA_  400                  // in_proj A width (q stored once, padded)
#define KPO_  768                  // out/xp W K' (3 terms x 256)
#define WAO_  512                  // out/xp A width ({hi,lo})

// amax scalars: 8 slots x 64B apart to break single-address atomic serialization
#define NSLOT 8
#define SSTR  16                   // floats between slots (64 B)
#define SCALW 128                  // floats per logical scalar (8 slots)

typedef __attribute__((ext_vector_type(8))) short short8;
typedef __attribute__((ext_vector_type(4))) float f32x4;
typedef unsigned short ushort;

#if defined(__has_builtin)
#if __has_builtin(__builtin_amdgcn_global_load_lds)
#define USE_GLD 1
#endif
#endif
#ifndef USE_GLD
#define USE_GLD 0
#endif

// ---- helpers ---------------------------------------------------------------
__device__ __forceinline__ void atomicMaxF(float* a, float v) {
  atomicMax(reinterpret_cast<int*>(a), __float_as_int(v));
}

// faithful fq: s = max(mx,1e-8)/127 where mx = max over the 8 slots
__device__ __forceinline__ float fq_scale(const float* pmax) {
  float m = pmax[0];
  #pragma unroll
  for (int i = 1; i < NSLOT; i++) m = fmaxf(m, pmax[i * SSTR]);
  return fmaxf(m, 1e-8f) / 127.f;
}
__device__ __forceinline__ float fq_apply(float x, float s) {
  float r = rintf(x / s);
  r = fminf(fmaxf(r, -128.f), 127.f);
  return r * s;
}

__device__ __forceinline__ ushort f2bf(float f) {  // round-to-nearest-even
  union { float f; unsigned u; } v; v.f = f;
  unsigned r = v.u + 0x7FFF + ((v.u >> 16) & 1);
  return (ushort)(r >> 16);
}
__device__ __forceinline__ float bf2f(ushort h) {
  union { unsigned u; float f; } v; v.u = ((unsigned)h) << 16;
  return v.f;
}

// block max -> atomicMax into one of 8 slots (by block id). sm >= blockDim/64.
__device__ __forceinline__ void blockAtomicMax(float v, float* out, float* sm) {
  #pragma unroll
  for (int o = 32; o > 0; o >>= 1) v = fmaxf(v, __shfl_down(v, o));
  if ((threadIdx.x & 63) == 0) sm[threadIdx.x >> 6] = v;
  __syncthreads();
  if (threadIdx.x == 0) {
    int nw = (blockDim.x + 63) >> 6;
    for (int i = 1; i < nw; i++) v = fmaxf(v, sm[i]);
    int slot = (blockIdx.x + blockIdx.y * 4 + blockIdx.z) & (NSLOT - 1);
    atomicMaxF(out + slot * SSTR, v);
  }
}

// ---- setup: weight splits + A2IN pad zero + scalar zero, one launch ---------
__device__ __forceinline__ void wsplit_body(const float* __restrict__ W,
                                            ushort* __restrict__ out,
                                            int K, int N, int Kw, int Kp,
                                            long total, int terms, long idx) {
  if (idx >= total) return;
  int k = (int)(idx % Kp);
  int n = (int)(idx / Kp);
  int t = k / Kw, kk = k - t * Kw;
  ushort r = 0;
  if (n < N && kk < K) {
    float w = W[(long)kk * N + n];
    ushort hi = f2bf(w);
    r = (t == terms - 1) ? f2bf(w - bf2f(hi)) : hi;
  }
  out[idx] = r;
}

__global__ __launch_bounds__(256) void k_setup(const float* __restrict__ in_w,
                                               const float* __restrict__ outw,
                                               const float* __restrict__ xpw,
                                               ushort* __restrict__ W2TI,
                                               ushort* __restrict__ W2TO,
                                               ushort* __restrict__ W2TX,
                                               ushort* __restrict__ A2IN,
                                               float* __restrict__ SCAL) {
  int bid = blockIdx.x;
  if (bid < 3200) {                       // in_w splits (2 x 1600)
    int blk = bid / 1600;
    long idx = (long)(bid % 1600) * 256 + threadIdx.x;
    wsplit_body(in_w + (long)blk * DM_ * 512, W2TI + (long)blk * 512 * KPI_,
                DM_, 512, KPA_, KPI_, 512L * KPI_, 2, idx);
    return;
  }
  bid -= 3200;
  if (bid < 3072) {                       // outw splits (2 x 1536)
    int blk = bid / 1536;
    long idx = (long)(bid % 1536) * 256 + threadIdx.x;
    wsplit_body(outw + (long)blk * DI_ * DM_, W2TO + (long)blk * 512 * KPO_,
                DI_, DM_, 256, KPO_, 512L * KPO_, 3, idx);
    return;
  }
  bid -= 3072;
  if (bid < 768) {                        // xpw splits (2 x 384)
    int blk = bid / 384;
    long idx = (long)(bid % 384) * 256 + threadIdx.x;
    wsplit_body(xpw + (long)blk * DI_ * 33, W2TX + (long)blk * 128 * KPO_,
                DI_, 33, 256, KPO_, 128L * KPO_, 3, idx);
    return;
  }
  bid -= 768;
  if (bid < 1200) {                       // A2IN pad zero (ROWS_*15 elems)
    long idx = (long)bid * 256 + threadIdx.x;
    long m = idx / 15; int c = (int)(idx - m * 15);
    A2IN[m * KPA_ + 385 + c] = 0;
    return;
  }
  bid -= 1200;                            // zero 8*256 scalar floats
  SCAL[bid * 256 + threadIdx.x] = 0.f;
}

// ---- fused absmax of x (1024 blk), pos (256 blk), pew (1 blk), float4 -------
__global__ __launch_bounds__(256) void k_absmax3(const float* __restrict__ x,
                                                 const float* __restrict__ pos,
                                                 const float* __restrict__ pew,
                                                 float* __restrict__ sx,
                                                 float* __restrict__ spos,
                                                 float* __restrict__ spew) {
  __shared__ float smr[8];
  int bid = blockIdx.x;
  float m = 0.f;
  if (bid < 1024) {
    const float4* p = (const float4*)x;
    const long n4 = (long)B_ * H_ * W_ / 4;
    for (long i = (long)bid * 256 + threadIdx.x; i < n4; i += 1024L * 256) {
      float4 v = p[i];
      m = fmaxf(m, fmaxf(fmaxf(fabsf(v.x), fabsf(v.y)), fmaxf(fabsf(v.z), fabsf(v.w))));
    }
    blockAtomicMax(m, sx, smr);
  } else if (bid < 1280) {
    const float4* p = (const float4*)pos;
    const long n4 = LDM_ / 4;
    for (long i = (long)(bid - 1024) * 256 + threadIdx.x; i < n4; i += 256L * 256) {
      float4 v = p[i];
      m = fmaxf(m, fmaxf(fmaxf(fabsf(v.x), fabsf(v.y)), fmaxf(fabsf(v.z), fabsf(v.w))));
    }
    blockAtomicMax(m, spos, smr);
  } else {
    for (int i = threadIdx.x; i < EMB * 32; i += 256) m = fmaxf(m, fabsf(pew[i]));
    blockAtomicMax(m, spew, smr);
  }
}

// simple elementwise fq into a fresh buffer (patch weights only; tiny)
__global__ void k_qx(const float* __restrict__ src, float* __restrict__ dst, long n,
                     const float* __restrict__ pmax) {
  float s = fq_scale(pmax);
  for (long i = (long)blockIdx.x * blockDim.x + threadIdx.x; i < n;
       i += (long)gridDim.x * blockDim.x)
    dst[i] = fq_apply(src[i], s);
}

// vectorized fq: dst4 = fq(src4); optional absmax -> nextmax; optional bf16
// q-emit into A2 [M][KPA_]. dst may == src.
__global__ void k_fq4(const float4* __restrict__ src, float4* __restrict__ dst, long n4,
                      const float* __restrict__ pmax, float* __restrict__ nextmax,
                      ushort* __restrict__ a2) {
  __shared__ float smr[8];
  float s = fq_scale(pmax);
  float m = 0.f;
  for (long i = (long)blockIdx.x * blockDim.x + threadIdx.x; i < n4;
       i += (long)gridDim.x * blockDim.x) {
    float4 v = src[i];
    float r0 = fminf(fmaxf(rintf(v.x / s), -128.f), 127.f);
    float r1 = fminf(fmaxf(rintf(v.y / s), -128.f), 127.f);
    float r2 = fminf(fmaxf(rintf(v.z / s), -128.f), 127.f);
    float r3 = fminf(fmaxf(rintf(v.w / s), -128.f), 127.f);
    float4 q = make_float4(r0 * s, r1 * s, r2 * s, r3 * s);
    dst[i] = q;
    m = fmaxf(m, fmaxf(fmaxf(fabsf(q.x), fabsf(q.y)), fmaxf(fabsf(q.z), fabsf(q.w))));
    if (a2) {
      long ii = i * 4;
      long mm = ii / 385; int kk = (int)(ii - mm * 385);
      float rr[4] = {r0, r1, r2, r3};
      #pragma unroll
      for (int j = 0; j < 4; j++) {
        a2[mm * KPA_ + kk] = f2bf(rr[j]);
        if (++kk == 385) { kk = 0; mm++; }
      }
    }
  }
  if (nextmax) blockAtomicMax(m, nextmax, smr);
}

// x4[i] = fq(x4[i], s_pmax) + p2[i % LDM/4]; absmax -> nextmax
__global__ void k_addpos4(float4* __restrict__ x, const float4* __restrict__ p2,
                          const float* __restrict__ pmax, float* __restrict__ nextmax) {
  __shared__ float smr[8];
  float s = fq_scale(pmax);
  float m = 0.f;
  const long n4 = NX_ / 4, l4 = LDM_ / 4;
  for (long i = (long)blockIdx.x * blockDim.x + threadIdx.x; i < n4;
       i += (long)gridDim.x * blockDim.x) {
    float4 v = x[i];
    float4 p = p2[i % l4];
    float4 o;
    o.x = fq_apply(v.x, s) + p.x;
    o.y = fq_apply(v.y, s) + p.y;
    o.z = fq_apply(v.z, s) + p.z;
    o.w = fq_apply(v.w, s) + p.w;
    x[i] = o;
    m = fmaxf(m, fmaxf(fmaxf(fabsf(o.x), fabsf(o.y)), fmaxf(fabsf(o.z), fabsf(o.w))));
  }
  blockAtomicMax(m, nextmax, smr);
}

// ---- fused patch embed: LDS-staged x (fq inline), PRE-QUANTIZED weights -----
__global__ __launch_bounds__(320) void k_patchfq(const float* __restrict__ x,
                                                 const float* __restrict__ wq,
                                                 const float* __restrict__ peb,
                                                 const float* __restrict__ sx_,
                                                 float* __restrict__ out,
                                                 float* __restrict__ nextmax) {
  __shared__ float xs[2][64][20];   // [ph][gw_local][pw] padded to 20
  __shared__ float smr[8];
  int tid = threadIdx.x;
  int gwt = blockIdx.x, gh = blockIdx.y, b = blockIdx.z;
  float sx = fq_scale(sx_);
  if (tid < 256) {
    int gwl = tid >> 2, pw = (tid & 3) * 4;
    #pragma unroll
    for (int ph = 0; ph < 2; ph++) {
      const float* src = x + ((long)b * H_ + gh * 2 + ph) * W_ + (long)gwt * 1024 + tid * 4;
      float4 v = *reinterpret_cast<const float4*>(src);
      xs[ph][gwl][pw + 0] = fq_apply(v.x, sx);
      xs[ph][gwl][pw + 1] = fq_apply(v.y, sx);
      xs[ph][gwl][pw + 2] = fq_apply(v.z, sx);
      xs[ph][gwl][pw + 3] = fq_apply(v.w, sx);
    }
  }
  __syncthreads();
  float mx = 0.f;
  if (tid < 280) {
    int e = tid % 35;
    int g0 = (tid / 35) * 8;
    float w[32];
    #pragma unroll
    for (int j = 0; j < 32; j++) w[j] = wq[e * 32 + j];
    float bias = peb[e];
    long obase = ((long)b * GW_ + (long)gwt * 64) * DM_ + gh * 35 + e;
    #pragma unroll
    for (int gi = 0; gi < 8; gi++) {
      int gw = g0 + gi;
      float acc = bias;
      #pragma unroll
      for (int pw = 0; pw < 16; pw++) {
        acc = fmaf(xs[0][gw][pw], w[pw], acc);
        acc = fmaf(xs[1][gw][pw], w[16 + pw], acc);
      }
      out[obase + (long)gw * DM_] = acc;
      mx = fmaxf(mx, fabsf(acc));
    }
  }
  blockAtomicMax(mx, nextmax, smr);
}

// ---- activation split: (Y0+Y1)[M][256] f32 -> A2[M][512] bf16 {hi,lo} -------
__global__ void k_asplit2(const float* __restrict__ Y, ushort* __restrict__ A2) {
  long idx = (long)blockIdx.x * 256 + threadIdx.x;   // M*512 threads
  long m = idx >> 9; int k = (int)(idx & 511);
  int t = k >> 8, kk = k & 255;
  float v = Y[m * DI_ + kk] + Y[(m + ROWS_) * DI_ + kk];
  ushort hi = f2bf(v);
  A2[idx] = t ? f2bf(v - bf2f(hi)) : hi;
}

// ---- bf16 MFMA GEMM: C[M][Nreal] = scale * (A2[M][Wa,wrapped] @ W2T[Npad][Kp]^T)
// LDS granule swizzle (rule #21, both-sides): granule id holds (row=id>>2,
// sl=(id&3)^((row>>1)&3)); reads use the same involution -> bank-quad
// coverage is uniform (4x per 32 lanes, the b128 minimum). Writes are the
// lane-linear global_load_lds DMA (conflict-free). Global source is
// per-lane pre-swizzled. 1-D grid NT*MT for XCD L2 A-panel sharing.
template<bool AMAX>
__global__ __launch_bounds__(256) void k_mgemm(const ushort* __restrict__ A2,
                                               const ushort* __restrict__ W2T,
                                               float* __restrict__ C,
                                               int Nreal, int Kp, int Wa, int MT,
                                               const float* __restrict__ sptr,
                                               float* __restrict__ amax_out) {
  __shared__ ushort Alds[4096];   // 512 granules x 16B, 8 KB
  __shared__ ushort Blds[4096];
  __shared__ float smr[8];
  int tid = threadIdx.x;
  int lane = tid & 63, wave = tid >> 6;
  int wm = wave >> 1, wn = wave & 1;
  int bid = blockIdx.x;
  int m0 = (bid % MT) * 128, n0 = (bid / MT) * 128;
  f32x4 acc[4][4];
  #pragma unroll
  for (int i = 0; i < 4; i++)
    #pragma unroll
    for (int j = 0; j < 4; j++) acc[i][j] = (f32x4){0.f, 0.f, 0.f, 0.f};

  for (int k0 = 0; k0 < Kp; k0 += 32) {
    #pragma unroll
    for (int r = 0; r < 2; r++) {
      int id = tid + r * 256;                       // granule 0..511
      int row = id >> 2;
      int sl = (id & 3) ^ ((row >> 1) & 3);         // inverse swizzle on source
      int kc = k0 + sl * 8; if (kc >= Wa) kc -= Wa; // A k-wrap (8-aligned)
      const ushort* ga = A2 + (long)(m0 + row) * Wa + kc;
      const ushort* gb = W2T + (long)(n0 + row) * Kp + k0 + sl * 8;
#if USE_GLD
      __builtin_amdgcn_global_load_lds(
          (const __attribute__((address_space(1))) unsigned int*)ga,
          (__attribute__((address_space(3))) unsigned int*)(Alds + id * 8), 16, 0, 0);
      __builtin_amdgcn_global_load_lds(
          (const __attribute__((address_space(1))) unsigned int*)gb,
          (__attribute__((address_space(3))) unsigned int*)(Blds + id * 8), 16, 0, 0);
#else
      short8 va = *reinterpret_cast<const short8*>(ga);
      *reinterpret_cast<short8*>(&Alds[id * 8]) = va;
      short8 vb = *reinterpret_cast<const short8*>(gb);
      *reinterpret_cast<short8*>(&Blds[id * 8]) = vb;
#endif
    }
    __syncthreads();
    int sl = lane >> 4, rr = lane & 15;
    short8 af[4], bf4[4];
    #pragma unroll
    for (int i = 0; i < 4; i++) {
      int rowA = wm * 64 + i * 16 + rr;
      af[i] = *reinterpret_cast<const short8*>(
          &Alds[(rowA * 4 + (sl ^ ((rowA >> 1) & 3))) * 8]);
    }
    #pragma unroll
    for (int j = 0; j < 4; j++) {
      int rowB = wn * 64 + j * 16 + rr;
      bf4[j] = *reinterpret_cast<const short8*>(
          &Blds[(rowB * 4 + (sl ^ ((rowB >> 1) & 3))) * 8]);
    }
    #pragma unroll
    for (int i = 0; i < 4; i++)
      #pragma unroll
      for (int j = 0; j < 4; j++)
        acc[i][j] = __builtin_amdgcn_mfma_f32_16x16x32_bf16(af[i], bf4[j], acc[i][j], 0, 0, 0);
    __syncthreads();
  }

  float s = sptr ? fq_scale(sptr) : 1.0f;
  float mx = 0.f;
  int cfr = lane & 15, rbase = (lane >> 4) * 4;
  #pragma unroll
  for (int i = 0; i < 4; i++) {
    int gmb = m0 + wm * 64 + i * 16 + rbase;
    #pragma unroll
    for (int j = 0; j < 4; j++) {
      int gn = n0 + wn * 64 + j * 16 + cfr;
      if (gn < Nreal) {
        #pragma unroll
        for (int rg = 0; rg < 4; rg++) {
          float v = acc[i][j][rg] * s;
          C[(long)(gmb + rg) * Nreal + gn] = v;
          mx = fmaxf(mx, fabsf(v));
        }
      }
    }
  }
  if (AMAX) blockAtomicMax(mx, amax_out, smr);
}

// ---- depthwise causal conv1d (K=4) + SiLU, BOTH dirs from one window --------
__global__ __launch_bounds__(256) void k_conv2(const float* __restrict__ xz,
                                               const float* __restrict__ cw,
                                               const float* __restrict__ cb,
                                               ushort* __restrict__ xch) {
  int d = threadIdx.x;
  int t0 = blockIdx.x * 16, b = blockIdx.y;
  long base = (long)b * L_;
  float w0 = cw[d * 4 + 0], w1 = cw[d * 4 + 1];
  float w2 = cw[d * 4 + 2], w3 = cw[d * 4 + 3];
  float bias = cb[d];
  float win[22];
  #pragma unroll
  for (int i = 0; i < 22; i++) {
    int t = t0 - 3 + i;
    win[i] = (t >= 0 && t < L_) ? xz[(base + t) * (2 * DI_) + d] : 0.f;
  }
  #pragma unroll
  for (int i = 0; i < 16; i++) {
    int t = t0 + i;
    float a0 = bias;
    a0 = fmaf(w0, win[i + 0], a0);
    a0 = fmaf(w1, win[i + 1], a0);
    a0 = fmaf(w2, win[i + 2], a0);
    a0 = fmaf(w3, win[i + 3], a0);
    float a1 = bias;
    a1 = fmaf(w0, win[i + 6], a1);
    a1 = fmaf(w1, win[i + 5], a1);
    a1 = fmaf(w2, win[i + 4], a1);
    a1 = fmaf(w3, win[i + 3], a1);
    float v0 = a0 * (1.f / (1.f + expf(-a0)));
    float v1 = a1 * (1.f / (1.f + expf(-a1)));
    long g0o = (base + t) * 512 + d;
    ushort h0 = f2bf(v0), h1 = f2bf(v1);
    xch[g0o] = h0;
    xch[g0o + 256] = f2bf(v0 - bf2f(h0));
    long g1o = ((long)ROWS_ + base + t) * 512 + d;
    xch[g1o] = h1;
    xch[g1o + 256] = f2bf(v1 - bf2f(h1));
  }
}

// ---- dt precompute into Y (scan2 reads dt then overwrites with y in place) --
__device__ __forceinline__ float softplusf(float x) {
  return fmaxf(x, 0.f) + log1pf(expf(-fabsf(x)));
}

__global__ __launch_bounds__(256) void k_dtp(const float* __restrict__ proj,
                                             const float* __restrict__ dtw,
                                             const float* __restrict__ dtb,
                                             float* __restrict__ dty) {
  __shared__ float pr[16][26];
  int d = threadIdx.x;
  long g0 = (long)blockIdx.x * 16;
  for (int i = threadIdx.x; i < 16 * DTR_; i += 256) {
    int r = i / DTR_, j = i - r * DTR_;
    pr[r][j] = proj[(g0 + r) * 33 + j];
  }
  float dwr[DTR_];
  #pragma unroll
  for (int r = 0; r < DTR_; r++) dwr[r] = dtw[r * DI_ + d];
  float dbv = dtb[d];
  __syncthreads();
  #pragma unroll
  for (int r = 0; r < 16; r++) {
    float acc = dbv;
    #pragma unroll
    for (int j = 0; j < DTR_; j++) acc = fmaf(pr[r][j], dwr[j], acc);
    dty[(g0 + r) * DI_ + d] = softplusf(acc);
  }
}

// ---- chunked parallel selective scan (exp-reduced, both dirs in grid.z) -----
__global__ __launch_bounds__(256) void k_scan1(const ushort* __restrict__ xch,
                                               const float* __restrict__ proj,
                                               const float* __restrict__ A_log,
                                               const float* __restrict__ dty,
                                               float* __restrict__ Hend,
                                               float* __restrict__ Pend) {
  int b = blockIdx.y, c = blockIdx.x, d = threadIdx.x, dir = blockIdx.z;
  float A[4];
  #pragma unroll
  for (int n = 0; n < 4; n++) A[n] = -expf(A_log[d * 4 + n]);
  bool fast = true;
  #pragma unroll
  for (int n = 1; n < 4; n++)
    fast = fast && (fabsf(A[n] - (float)(n + 1) * A[0]) <= 1e-4f * fabsf(A[n]));
  long base = (long)b * L_;
  int step0 = c * CHL_;
  long row0 = base + (dir ? (L_ - 1 - step0) : step0);
  long doff = (long)dir * ROWS_;
  int rs = dir ? -1 : 1;
  const float* pdt = dty + (doff + row0) * DI_ + d;
  const ushort* pxc = xch + (doff + row0) * 512 + d;
  const float* pp  = proj + (doff + row0) * 33;
  float h[4] = {0.f, 0.f, 0.f, 0.f};
  float sdt = 0.f;
  if (fast) {
    float A0 = A[0];
    for (int s = 0; s < CHL_; s++) {
      float dtv = *pdt;
      float xcv = bf2f(pxc[0]) + bf2f(pxc[256]);
      float dx = dtv * xcv;
      float e1 = expf(dtv * A0);
      float e2 = e1 * e1, e3 = e2 * e1, e4 = e3 * e1;
      h[0] = e1 * h[0] + dx * pp[DTR_ + 0];
      h[1] = e2 * h[1] + dx * pp[DTR_ + 1];
      h[2] = e3 * h[2] + dx * pp[DTR_ + 2];
      h[3] = e4 * h[3] + dx * pp[DTR_ + 3];
      sdt += dtv;
      pdt += (long)rs * DI_; pxc += (long)rs * 512; pp += rs * 33;
    }
  } else {
    for (int s = 0; s < CHL_; s++) {
      float dtv = *pdt;
      float xcv = bf2f(pxc[0]) + bf2f(pxc[256]);
      float dx = dtv * xcv;
      #pragma unroll
      for (int n = 0; n < 4; n++) {
        float dA = expf(dtv * A[n]);
        h[n] = dA * h[n] + dx * pp[DTR_ + n];
      }
      sdt += dtv;
      pdt += (long)rs * DI_; pxc += (long)rs * 512; pp += rs * 33;
    }
  }
  float P[4];
  #pragma unroll
  for (int n = 0; n < 4; n++) P[n] = expf(A[n] * sdt);
  long o = (((long)dir * B_ + b) * CH_ + c) * 1024 + d * 4;
  *reinterpret_cast<float4*>(Hend + o) = make_float4(h[0], h[1], h[2], h[3]);
  *reinterpret_cast<float4*>(Pend + o) = make_float4(P[0], P[1], P[2], P[3]);
}

__global__ __launch_bounds__(256) void k_carry(const float* __restrict__ Hend,
                                               const float* __restrict__ Pend,
                                               float* __restrict__ Carry) {
  int tid = blockIdx.x * 256 + threadIdx.x;   // 2*B_*1024 lanes
  int be = tid >> 10, i = tid & 1023;         // be = dir*16+b
  float carry = 0.f;
  for (int c = 0; c < CH_; c++) {
    long o = ((long)be * CH_ + c) * 1024 + i;
    Carry[o] = carry;
    carry = Pend[o] * carry + Hend[o];
  }
}

// dty holds dt on entry; read-once-then-overwrite with y (same thread).
__global__ __launch_bounds__(256) void k_scan2(const ushort* __restrict__ xch,
                                               const float* __restrict__ proj,
                                               const float* __restrict__ A_log,
                                               const float* __restrict__ Dp,
                                               const float* __restrict__ xz,
                                               const float* __restrict__ Carry,
                                               float* dty) {
  int b = blockIdx.y, c = blockIdx.x, d = threadIdx.x, dir = blockIdx.z;
  float A[4];
  #pragma unroll
  for (int n = 0; n < 4; n++) A[n] = -expf(A_log[d * 4 + n]);
  bool fast = true;
  #pragma unroll
  for (int n = 1; n < 4; n++)
    fast = fast && (fabsf(A[n] - (float)(n + 1) * A[0]) <= 1e-4f * fabsf(A[n]));
  long base = (long)b * L_;
  int step0 = c * CHL_;
  long row0 = base + (dir ? (L_ - 1 - step0) : step0);
  long doff = (long)dir * ROWS_;
  int rs = dir ? -1 : 1;
  float* pdy = dty + (doff + row0) * DI_ + d;
  const ushort* pxc = xch + (doff + row0) * 512 + d;
  const float* pz  = xz + row0 * (2 * DI_) + DI_ + d;
  const float* pp  = proj + (doff + row0) * 33;
  long o = (((long)dir * B_ + b) * CH_ + c) * 1024 + d * 4;
  float4 cv = *reinterpret_cast<const float4*>(Carry + o);
  float h[4] = {cv.x, cv.y, cv.z, cv.w};
  float Dv = Dp[d];
  if (fast) {
    float A0 = A[0];
    for (int s = 0; s < CHL_; s++) {
      float dtv = *pdy;
      float xcv = bf2f(pxc[0]) + bf2f(pxc[256]);
      float zv  = *pz;
      float dx = dtv * xcv;
      float e1 = expf(dtv * A0);
      float e2 = e1 * e1, e3 = e2 * e1, e4 = e3 * e1;
      h[0] = e1 * h[0] + dx * pp[DTR_ + 0];
      h[1] = e2 * h[1] + dx * pp[DTR_ + 1];
      h[2] = e3 * h[2] + dx * pp[DTR_ + 2];
      h[3] = e4 * h[3] + dx * pp[DTR_ + 3];
      float acc = 0.f;
      acc = fmaf(h[0], pp[DTR_ + N_ + 0], acc);
      acc = fmaf(h[1], pp[DTR_ + N_ + 1], acc);
      acc = fmaf(h[2], pp[DTR_ + N_ + 2], acc);
      acc = fmaf(h[3], pp[DTR_ + N_ + 3], acc);
      float yv = fmaf(Dv, xcv, acc);
      float sig = 1.f / (1.f + expf(-zv));
      yv *= zv * sig;
      *pdy = yv;
      pdy += (long)rs * DI_; pxc += (long)rs * 512;
      pz += rs * (2 * DI_); pp += rs * 33;
    }
  } else {
    for (int s = 0; s < CHL_; s++) {
      float dtv = *pdy;
      float xcv = bf2f(pxc[0]) + bf2f(pxc[256]);
      float zv  = *pz;
      float dx = dtv * xcv;
      float acc = 0.f;
      #pragma unroll
      for (int n = 0; n < 4; n++) {
        float dA = expf(dtv * A[n]);
        h[n] = dA * h[n] + dx * pp[DTR_ + n];
        acc = fmaf(h[n], pp[DTR_ + N_ + n], acc);
      }
      float yv = fmaf(Dv, xcv, acc);
      float sig = 1.f / (1.f + expf(-zv));
      yv *= zv * sig;
      *pdy = yv;
      pdy += (long)rs * DI_; pxc += (long)rs * 512;
      pz += rs * (2 * DI_); pp += rs * 33;
    }
  }
}

// ---- residual + fq(mamba_out) + layernorm, wave-per-row ----------------------
__global__ __launch_bounds__(256) void k_ln(const float* __restrict__ x2,
                                            float* __restrict__ mo,
                                            const float* __restrict__ smo,
                                            const float* __restrict__ g,
                                            const float* __restrict__ bta,
                                            float* __restrict__ nextmax) {
  __shared__ float smr[4];
  int lane = threadIdx.x & 63;
  int wid = blockIdx.x * 4 + (threadIdx.x >> 6);
  float s = fq_scale(smo);
  float wmax = 0.f;
  for (int row = wid; row < ROWS_; row += 2560) {
    const float* xr = x2 + (long)row * DM_;
    float* mr = mo + (long)row * DM_;
    float v[7];
    float lsum = 0.f;
    #pragma unroll
    for (int k = 0; k < 6; k++) {
      int c = lane + k * 64;
      v[k] = xr[c] + fq_apply(mr[c], s);
      lsum += v[k];
    }
    v[6] = 0.f;
    if (lane == 0) v[6] = xr[384] + fq_apply(mr[384], s);
    lsum += v[6];
    #pragma unroll
    for (int o = 32; o > 0; o >>= 1) lsum += __shfl_xor(lsum, o);
    float mean = lsum / 385.f;
    float lvar = 0.f;
    #pragma unroll
    for (int k = 0; k < 6; k++) { float dd = v[k] - mean; lvar += dd * dd; }
    if (lane == 0) { float dd = v[6] - mean; lvar += dd * dd; }
    #pragma unroll
    for (int o = 32; o > 0; o >>= 1) lvar += __shfl_xor(lvar, o);
    float rs = 1.f / sqrtf(lvar / 385.f + 1e-5f);
    #pragma unroll
    for (int k = 0; k < 6; k++) {
      int c = lane + k * 64;
      float o2 = (v[k] - mean) * rs * g[c] + bta[c];
      mr[c] = o2;
      wmax = fmaxf(wmax, fabsf(o2));
    }
    if (lane == 0) {
      float o2 = (v[6] - mean) * rs * g[384] + bta[384];
      mr[384] = o2;
      wmax = fmaxf(wmax, fabsf(o2));
    }
  }
  blockAtomicMax(wmax, nextmax, smr);
}

// ---- mean pool over L (two-stage, coalesced, deterministic) ------------------
__global__ __launch_bounds__(256) void k_pool1(const float* __restrict__ x2,
                                               float* __restrict__ part) {
  int b = blockIdx.x, ch = blockIdx.y, tid = threadIdx.x;
  float s0 = 0.f, s1 = 0.f;
  for (int l = ch * 64; l < ch * 64 + 64; l++) {
    const float* row = x2 + ((long)b * L_ + l) * DM_;
    s0 += row[tid];
    if (tid < DM_ - 256) s1 += row[tid + 256];
  }
  long o = ((long)b * 20 + ch) * DM_;
  part[o + tid] = s0;
  if (tid < DM_ - 256) part[o + tid + 256] = s1;
}

// blocks 0..24: pool reduce + amax(pool) -> spool; blocks 25..28: amax(clsw) -> sclsw
__global__ void k_pool2c(const float* __restrict__ part, float* __restrict__ pool,
                         const float* __restrict__ clsw,
                         float* __restrict__ spool, float* __restrict__ sclsw) {
  __shared__ float smr[8];
  int bid = blockIdx.x;
  if (bid < 25) {
    int idx = bid * 256 + threadIdx.x;
    float mv = 0.f;
    if (idx < B_ * DM_) {
      int b = idx / DM_, c = idx % DM_;
      float s = 0.f;
      for (int ch = 0; ch < 20; ch++) s += part[((long)b * 20 + ch) * DM_ + c];
      float mean = s / (float)L_;
      pool[idx] = mean;
      mv = fabsf(mean);
    }
    blockAtomicMax(mv, spool, smr);
  } else {
    float m = 0.f;
    for (int i = (bid - 25) * 256 + threadIdx.x; i < DM_ * 2; i += 4 * 256)
      m = fmaxf(m, fabsf(clsw[i]));
    blockAtomicMax(m, sclsw, smr);
  }
}

// ---- classifier (parallel): grid 32 = (b,c), 128 threads reduce over K=385 --
__global__ __launch_bounds__(128) void k_cls(const float* __restrict__ pool,
                                             const float* __restrict__ clsw,
                                             const float* __restrict__ clsb,
                                             const float* __restrict__ sp_,
                                             const float* __restrict__ sw_,
                                             float* __restrict__ out) {
  __shared__ float smr[2];
  int b = blockIdx.x >> 1, c = blockIdx.x & 1;
  float sp = fq_scale(sp_), sw = fq_scale(sw_);
  float acc = 0.f;
  for (int k = threadIdx.x; k < DM_; k += 128) {
    float xv = fq_apply(pool[b * DM_ + k], sp);
    float wv = fq_apply(clsw[k * 2 + c], sw);
    acc = fmaf(xv, wv, acc);
  }
  #pragma unroll
  for (int o = 32; o > 0; o >>= 1) acc += __shfl_down(acc, o);
  if ((threadIdx.x & 63) == 0) smr[threadIdx.x >> 6] = acc;
  __syncthreads();
  if (threadIdx.x == 0) out[blockIdx.x] = smr[0] + smr[1] + clsb[c];
}

// ---- launch ------------------------------------------------------------------
extern "C" void kernel_launch(void* const* d_in, const int* in_sizes, int n_in,
                              void* d_out, int out_size, void* d_ws, size_t ws_size,
                              hipStream_t stream) {
  const float* x    = (const float*)d_in[0];
  const float* pew  = (const float*)d_in[1];
  const float* peb  = (const float*)d_in[2];
  const float* pos  = (const float*)d_in[3];
  const float* in_w = (const float*)d_in[4];
  const float* cw   = (const float*)d_in[5];
  const float* cb   = (const float*)d_in[6];
  const float* xpw  = (const float*)d_in[7];
  const float* dtw  = (const float*)d_in[8];
  const float* dtb  = (const float*)d_in[9];
  const float* alog = (const float*)d_in[10];
  const float* dp   = (const float*)d_in[11];
  const float* outw = (const float*)d_in[12];
  const float* lng  = (const float*)d_in[13];
  const float* lnb  = (const float*)d_in[14];
  const float* clsw = (const float*)d_in[15];
  const float* clsb = (const float*)d_in[16];

  float* ws    = (float*)d_ws;
  float* SCAL  = ws;                              // 13 scalars x 128 floats (8 slots)
  float* WQ    = ws + 2048;                       // 2048 (1120 used)
  float* P2    = WQ + 2048;                       // 492,800
  float* X2    = P2 + LDM_;                       // 7,884,800
  float* XZ    = X2 + NX_;                        // 10,485,760
  float* XCH_f = XZ + (long)ROWS_ * 512;          // 10,485,760 (ushort [40960][512])
  float* PROJ  = XCH_f + 2L * ROWS_ * DI_;        // 40960*33 = 1,351,680
  float* Y     = PROJ + 2L * ROWS_ * 33;          // 2 x 5,242,880 (dt -> y in place)
  float* MO    = Y + 2L * ROWS_ * DI_;            // 7,884,800
  float* POOL  = MO + NX_;                        // 8,192
  float* PART  = POOL + 8192;                     // 123,200 (+pad)
  float* A2IN_f= PART + 131072;                   // 4,096,000 f (ushort overlay)
  float* W2I_f = A2IN_f + 4096000;                // 409,600 f
  float* W2O_f = W2I_f + 409600;                  // 393,216 f
  float* W2X_f = W2O_f + 393216;                  // 98,304 f (2 x [128][768] ushort)
  // aliases (disjoint lifetimes):
  float*  HEND = MO;                              // scan summaries, dead before out-GEMM
  float*  PEND = MO + 2097152;
  float*  CARR = MO + 4194304;
  ushort* A2Y  = (ushort*)XZ;                     // [20480][512], dead before next in-GEMM
  ushort* XCH  = (ushort*)XCH_f;                  // xc bf16 {hi|lo} [40960][512]
  ushort* A2IN = (ushort*)A2IN_f;                 // [20480][400]
  ushort* W2TI = (ushort*)W2I_f;                  // 2 x [512][800]
  ushort* W2TO = (ushort*)W2O_f;                  // 2 x [512][768]
  ushort* W2TX = (ushort*)W2X_f;                  // 2 x [128][768]

  // scalar entry i lives at SCAL + i*SCALW (8 slots, 64B apart)
  #define SC(i) (SCAL + (i) * SCALW)

  // one consolidated setup launch: all weight splits + A2IN pad + SCAL zero
  k_setup<<<8248, 256, 0, stream>>>(in_w, outw, xpw, W2TI, W2TO, W2TX, A2IN, SCAL);

  // fused absmax of x / pos / pew (one launch), then pre-quantize patch weights
  k_absmax3<<<1281, 256, 0, stream>>>(x, pos, pew, SC(0), SC(4), SC(1));
  k_qx<<<5, 256, 0, stream>>>(pew, WQ, EMB * 2 * 16, SC(1));
  k_patchfq<<<dim3(20, 11, 16), 320, 0, stream>>>(x, WQ, peb, SC(0), X2, SC(2));

  // pos = fq(fq(pos_embed)) == fq(pos_embed)  (fq idempotent)
  k_fq4<<<512, 256, 0, stream>>>((const float4*)pos, (float4*)P2, LDM_ / 4,
                                 SC(4), nullptr, nullptr);

  // x = fq(fq(x) + pos) with inner fq(x) = fq(patch_out, s2) (outer chain identity)
  k_addpos4<<<2048, 256, 0, stream>>>((float4*)X2, (const float4*)P2, SC(2), SC(6));
  k_fq4<<<2048, 256, 0, stream>>>((const float4*)X2, (float4*)X2, NX_ / 4,
                                  SC(6), nullptr, A2IN);

  const float* in_scale[2] = {SC(6), SC(8)};
  for (int blk = 0; blk < 2; blk++) {
    // in-proj: XZ = s * (q @ [w_hi; w_lo])   (MFMA bf16, A k-wrapped at 400)
    k_mgemm<false><<<640, 256, 0, stream>>>(
        A2IN, W2TI + (long)blk * 512 * KPI_, XZ, 512, KPI_, KPA_, 160,
        in_scale[blk], nullptr);
    // conv both dirs -> xc bf16 {hi|lo}; xp-proj via MFMA (N=33 in one tile)
    k_conv2<<<dim3(80, 16), 256, 0, stream>>>(XZ, cw + blk * DI_ * K_,
                                              cb + blk * DI_, XCH);
    k_mgemm<false><<<320, 256, 0, stream>>>(
        XCH, W2TX + (long)blk * 128 * KPO_, PROJ, 33, KPO_, WAO_, 320,
        nullptr, nullptr);
    k_dtp<<<2560, 256, 0, stream>>>(PROJ, dtw + blk * DTR_ * DI_, dtb + blk * DI_, Y);
    k_scan1<<<dim3(CH_, B_, 2), 256, 0, stream>>>(XCH, PROJ, alog + blk * DI_ * N_,
                                                  Y, HEND, PEND);
    k_carry<<<128, 256, 0, stream>>>(HEND, PEND, CARR);
    k_scan2<<<dim3(CH_, B_, 2), 256, 0, stream>>>(XCH, PROJ, alog + blk * DI_ * N_,
                                                  dp + blk * DI_, XZ, CARR, Y);
    // out-proj: MO = [y_hi | y_lo] (wrapped) @ [w_hi; w_hi; w_lo]  (amax fused)
    k_asplit2<<<40960, 256, 0, stream>>>(Y, A2Y);
    k_mgemm<true><<<640, 256, 0, stream>>>(
        A2Y, W2TO + (long)blk * 512 * KPO_, MO, DM_, KPO_, WAO_, 160,
        nullptr, SC(7 + blk * 2));
    // x = fq(layernorm(x + fq(mo))); emit q for next block's in-proj
    k_ln<<<640, 256, 0, stream>>>(X2, MO, SC(7 + blk * 2),
                                  lng + blk * DM_, lnb + blk * DM_, SC(8 + blk * 2));
    k_fq4<<<2048, 256, 0, stream>>>((const float4*)MO, (float4*)X2, NX_ / 4,
                                    SC(8 + blk * 2), nullptr,
                                    blk == 0 ? A2IN : nullptr);
  }

  // mean-pool (2-stage, clsw amax folded into stage 2), fq, classifier
  k_pool1<<<dim3(16, 20), 256, 0, stream>>>(X2, PART);
  k_pool2c<<<29, 256, 0, stream>>>(PART, POOL, clsw, SC(11), SC(12));
  k_cls<<<32, 128, 0, stream>>>(POOL, clsw, clsb, SC(11), SC(12), (float*)d_out);
}